// Round 3
// baseline (6216.848 us; speedup 1.0000x reference)
//
#include <hip/hip_runtime.h>

#define NXg 512
#define NYg 512
#define NNg (NXg*NYg)
#define TPB 256
#define NBT 512            // total blocks; __launch_bounds__(256,2) guarantees co-residency
#define NBC 128            // blocks per channel
#define NSTEPS 8
#define CGIT 10
#define DTf (1.0f/64.0f)
#define H2I 256.0f         // 1/h^2

// ---- software grid barrier (sense-reversing, device scope) ----
__device__ __forceinline__ void gbar(int* cnt, int* gen) {
  __syncthreads();
  if (threadIdx.x == 0) {
    __threadfence();   // release: publish this block's global stores device-wide
    const int g = __hip_atomic_load(gen, __ATOMIC_RELAXED, __HIP_MEMORY_SCOPE_AGENT);
    const int a = __hip_atomic_fetch_add(cnt, 1, __ATOMIC_ACQ_REL, __HIP_MEMORY_SCOPE_AGENT);
    if (a == NBT - 1) {
      __hip_atomic_store(cnt, 0, __ATOMIC_RELAXED, __HIP_MEMORY_SCOPE_AGENT);
      __hip_atomic_store(gen, g + 1, __ATOMIC_RELEASE, __HIP_MEMORY_SCOPE_AGENT);
    } else {
      while (__hip_atomic_load(gen, __ATOMIC_RELAXED, __HIP_MEMORY_SCOPE_AGENT) == g)
        __builtin_amdgcn_s_sleep(2);
    }
    __threadfence();   // acquire: see all other blocks' stores
  }
  __syncthreads();
}

// deterministic block-wide sum, identical result in all threads
__device__ __forceinline__ float block_sum(float v, float* lds) {
  #pragma unroll
  for (int off = 32; off > 0; off >>= 1) v += __shfl_down(v, off, 64);
  const int lane = threadIdx.x & 63;
  const int w    = threadIdx.x >> 6;
  if (lane == 0) lds[w] = v;
  __syncthreads();
  float s = (lds[0] + lds[1]) + (lds[2] + lds[3]);
  __syncthreads();
  return s;
}

__global__ void __launch_bounds__(TPB, 2)
dr_sw(const float* __restrict__ U0, const float* __restrict__ scale,
      const float* __restrict__ K1, const float* __restrict__ K2,
      const float* __restrict__ K3, float* __restrict__ out,
      float* __restrict__ ws)
{
  __shared__ float lds[4];
  __shared__ float sW[384];   // K1(64) | K2(256) | K3(64)

  for (int i = threadIdx.x; i < 384; i += TPB) {
    float w;
    if (i < 64)       w = K1[i];
    else if (i < 320) w = K2[i - 64];
    else              w = K3[i - 320];
    sW[i] = w;
  }

  int*   cnt   = (int*)ws;          // barrier counter (zeroed by host each call)
  int*   gen   = (int*)ws + 32;     // barrier generation (128 B away)
  float* partA = ws + 64;           // [4][NBC] pAp partials
  float* partB = partA + 4*NBC;     // [4][NBC] r.r partials
  float* X  = ws + 1088;            // 4 planes: current U / CG solution
  float* R  = X  + 4*NNg;           // 4 planes: residual mirror (halo)
  float* P0 = R  + 4*NNg;           // 4 planes: p buffer A
  float* P1 = P0 + 4*NNg;           // 4 planes: p buffer B

  const int bid = blockIdx.x, tid = threadIdx.x;
  const int ch  = bid >> 7;            // channel 0..3
  const int blk = bid & 127;           // block within channel
  const int row = blk*4 + (tid >> 6);  // 4 rows per block
  const int col = (tid & 63) << 3;     // 8 cells per thread
  const int idx = row*NXg + col;
  const bool hasUp = (row > 0), hasDn = (row < NYg-1);
  const bool hasL  = (col > 0), hasR  = (col + 8 < NXg);
  const float gamma = 1.0f / (scale[ch] * DTf);   // matches reference bit-for-bit

  float* Xc = X + ch*NNg;
  float* Rc = R + ch*NNg;
  float* PbufA = P0 + ch*NNg;
  float* PbufB = P1 + ch*NNg;
  float* pA = partA + ch*NBC;
  float* pB = partB + ch*NBC;

  const int g2 = bid*TPB + tid;   // 0..131071 — flat mapping for deinterleave/MLP

  // de-interleave U0 (N,4) -> channel planes (2 cells per thread)
  #pragma unroll
  for (int c = 0; c < 2; ++c) {
    const int cell = g2 + c*(NNg/2);
    const float4 u = ((const float4*)U0)[cell];
    X[cell] = u.x; X[NNg+cell] = u.y; X[2*NNg+cell] = u.z; X[3*NNg+cell] = u.w;
  }
  gbar(cnt, gen);

  for (int step = 0; step < NSTEPS; ++step) {
    // ---- CG init: b = gamma*u, x0 = 0, r = b, rs = r.r ----
    float rr[8], xx[8], pold[8];
    {
      const float4 a = *(const float4*)(Xc + idx);
      const float4 b = *(const float4*)(Xc + idx + 4);
      rr[0]=gamma*a.x; rr[1]=gamma*a.y; rr[2]=gamma*a.z; rr[3]=gamma*a.w;
      rr[4]=gamma*b.x; rr[5]=gamma*b.y; rr[6]=gamma*b.z; rr[7]=gamma*b.w;
      #pragma unroll
      for (int k = 0; k < 8; ++k) { xx[k] = 0.f; pold[k] = 0.f; }
      *(float4*)(Rc + idx)     = make_float4(rr[0],rr[1],rr[2],rr[3]);
      *(float4*)(Rc + idx + 4) = make_float4(rr[4],rr[5],rr[6],rr[7]);
      // zero the it=0 "p_old" plane so halo reads are NaN-safe (ws is poisoned)
      *(float4*)(PbufB + idx)     = make_float4(0.f,0.f,0.f,0.f);
      *(float4*)(PbufB + idx + 4) = make_float4(0.f,0.f,0.f,0.f);
      float p = 0.f;
      #pragma unroll
      for (int k = 0; k < 8; ++k) p += rr[k]*rr[k];
      float bs = block_sum(p, lds);
      if (tid == 0) pB[blk] = bs;
    }
    gbar(cnt, gen);
    float rs = block_sum((tid < NBC) ? pB[tid] : 0.f, lds);
    float beta = 0.0f;
    float* Pcur = PbufA;
    float* Pold = PbufB;

    for (int it = 0; it < CGIT; ++it) {
      // phase A: p_new = r + beta*p_old (halo recomputed); Ap = A p_new; pAp
      float pn[8], Ap[8];
      #pragma unroll
      for (int k = 0; k < 8; ++k) pn[k] = rr[k] + beta*pold[k];
      if (it < CGIT-1) {  // last iteration's p is never read
        *(float4*)(Pcur + idx)     = make_float4(pn[0],pn[1],pn[2],pn[3]);
        *(float4*)(Pcur + idx + 4) = make_float4(pn[4],pn[5],pn[6],pn[7]);
      }

      float up[8], dn[8];
      #pragma unroll
      for (int k = 0; k < 8; ++k) { up[k] = 0.f; dn[k] = 0.f; }
      if (hasUp) {
        const float4 r0 = *(const float4*)(Rc + idx - NXg);
        const float4 r1 = *(const float4*)(Rc + idx - NXg + 4);
        const float4 p0 = *(const float4*)(Pold + idx - NXg);
        const float4 p1 = *(const float4*)(Pold + idx - NXg + 4);
        up[0]=r0.x+beta*p0.x; up[1]=r0.y+beta*p0.y; up[2]=r0.z+beta*p0.z; up[3]=r0.w+beta*p0.w;
        up[4]=r1.x+beta*p1.x; up[5]=r1.y+beta*p1.y; up[6]=r1.z+beta*p1.z; up[7]=r1.w+beta*p1.w;
      }
      if (hasDn) {
        const float4 r0 = *(const float4*)(Rc + idx + NXg);
        const float4 r1 = *(const float4*)(Rc + idx + NXg + 4);
        const float4 p0 = *(const float4*)(Pold + idx + NXg);
        const float4 p1 = *(const float4*)(Pold + idx + NXg + 4);
        dn[0]=r0.x+beta*p0.x; dn[1]=r0.y+beta*p0.y; dn[2]=r0.z+beta*p0.z; dn[3]=r0.w+beta*p0.w;
        dn[4]=r1.x+beta*p1.x; dn[5]=r1.y+beta*p1.y; dn[6]=r1.z+beta*p1.z; dn[7]=r1.w+beta*p1.w;
      }
      float lv = 0.f, rv = 0.f;
      if (hasL) lv = Rc[idx-1] + beta*Pold[idx-1];
      if (hasR) rv = Rc[idx+8] + beta*Pold[idx+8];

      float pAp = 0.f;
      #pragma unroll
      for (int k = 0; k < 8; ++k) {
        const float u = pn[k];
        float s = 0.f;
        if (hasUp) s += u - up[k];
        if (hasDn) s += u - dn[k];
        const float Lv = (k > 0) ? pn[k-1] : lv;
        if (k > 0 || hasL) s += u - Lv;
        const float Rv = (k < 7) ? pn[k+1] : rv;
        if (k < 7 || hasR) s += u - Rv;
        Ap[k] = s*H2I + gamma*u;
        pAp += u*Ap[k];
      }
      float bs = block_sum(pAp, lds);
      if (tid == 0) pA[blk] = bs;
      gbar(cnt, gen);   // sync 1
      const float pApT = block_sum((tid < NBC) ? pA[tid] : 0.f, lds);
      const float alpha = rs / pApT;
      #pragma unroll
      for (int k = 0; k < 8; ++k) { xx[k] += alpha*pn[k]; rr[k] -= alpha*Ap[k]; }

      if (it < CGIT-1) {
        // phase B: publish r, reduce r.r
        *(float4*)(Rc + idx)     = make_float4(rr[0],rr[1],rr[2],rr[3]);
        *(float4*)(Rc + idx + 4) = make_float4(rr[4],rr[5],rr[6],rr[7]);
        float rp = 0.f;
        #pragma unroll
        for (int k = 0; k < 8; ++k) rp += rr[k]*rr[k];
        float bs2 = block_sum(rp, lds);
        if (tid == 0) pB[blk] = bs2;
        gbar(cnt, gen); // sync 2
        const float rsn = block_sum((tid < NBC) ? pB[tid] : 0.f, lds);
        beta = rsn / rs;
        rs = rsn;
        #pragma unroll
        for (int k = 0; k < 8; ++k) pold[k] = pn[k];
        float* t = Pcur; Pcur = Pold; Pold = t;
      }
    }
    // publish solution
    *(float4*)(Xc + idx)     = make_float4(xx[0],xx[1],xx[2],xx[3]);
    *(float4*)(Xc + idx + 4) = make_float4(xx[4],xx[5],xx[6],xx[7]);
    gbar(cnt, gen);

    // ---- reaction: U += DT * tanh(tanh(tanh(U K1) K2) K3), flat mapping ----
    #pragma unroll
    for (int c = 0; c < 2; ++c) {
      const int cell = g2 + c*(NNg/2);
      float v0 = X[cell], v1 = X[NNg+cell], v2 = X[2*NNg+cell], v3 = X[3*NNg+cell];
      float h1[16], h2[16];
      #pragma unroll
      for (int h = 0; h < 16; ++h)
        h1[h] = tanhf(v0*sW[h] + v1*sW[16+h] + v2*sW[32+h] + v3*sW[48+h]);
      #pragma unroll
      for (int j = 0; j < 16; ++j) {
        float s = 0.f;
        #pragma unroll
        for (int h = 0; h < 16; ++h) s += h1[h]*sW[64 + 16*h + j];
        h2[j] = tanhf(s);
      }
      float o0=0.f,o1=0.f,o2=0.f,o3=0.f;
      #pragma unroll
      for (int j = 0; j < 16; ++j) {
        const float t = h2[j];
        o0 += t*sW[320 + 4*j + 0];
        o1 += t*sW[320 + 4*j + 1];
        o2 += t*sW[320 + 4*j + 2];
        o3 += t*sW[320 + 4*j + 3];
      }
      v0 += DTf*tanhf(o0); v1 += DTf*tanhf(o1);
      v2 += DTf*tanhf(o2); v3 += DTf*tanhf(o3);
      X[cell]=v0; X[NNg+cell]=v1; X[2*NNg+cell]=v2; X[3*NNg+cell]=v3;
      if (step == NSTEPS-1)
        ((float4*)out)[cell] = make_float4(v0, v1, v2, v3);
    }
    if (step < NSTEPS-1) gbar(cnt, gen);
  }
}

// diagnostic: runs ONLY if ws is too small — absmax ≈ 54321 tells us that.
__global__ void diag_ws(float* out) { out[0] = 54321.0f; }

extern "C" void kernel_launch(void* const* d_in, const int* in_sizes, int n_in,
                              void* d_out, int out_size, void* d_ws, size_t ws_size,
                              hipStream_t stream) {
  const float* U0    = (const float*)d_in[0];
  const float* scale = (const float*)d_in[1];
  const float* K1    = (const float*)d_in[2];
  const float* K2    = (const float*)d_in[3];
  const float* K3    = (const float*)d_in[4];
  float* out = (float*)d_out;
  float* ws  = (float*)d_ws;

  const size_t need = (size_t)(1088 + 16*NNg) * sizeof(float);
  if (ws_size < need) {
    hipLaunchKernelGGL(diag_ws, dim3(1), dim3(1), 0, stream, out);
    return;
  }
  // zero the barrier state (harness poisons ws with 0xAA before timing)
  hipMemsetAsync(ws, 0, 256, stream);
  hipLaunchKernelGGL(dr_sw, dim3(NBT), dim3(TPB), 0, stream,
                     U0, scale, K1, K2, K3, out, ws);
}